// Round 1
// baseline (323.528 us; speedup 1.0000x reference)
//
#include <hip/hip_runtime.h>

// Problem constants
#define NIMG 64
#define H 512
#define W 512
constexpr int TILE_ROWS = 16;       // rows per block in kernel A
constexpr int LDS_STRIDE = 516;     // 512 + 4 pad (keeps 16B alignment)

constexpr float THR_L1 = 50.0f / 255.0f;          // level_idx=1 (64x64 details)
constexpr float THR_L2 = 50.0f / 2.0f / 255.0f;   // level_idx=2 (128x128)
constexpr float THR_L3 = 50.0f / 4.0f / 255.0f;   // level_idx=3 (256x256)

__device__ __forceinline__ float wave_sum(float v) {
#pragma unroll
    for (int o = 32; o > 0; o >>= 1) v += __shfl_down(v, o, 64);
    return v;
}

__device__ __forceinline__ float clip01(float x) {
    return fminf(fmaxf(x, 0.0f), 1.0f);
}

// Kernel A: clip + n2v + tv + level-1 Haar DWT (writes ll1, 64x256x256)
// grid: 64 images * 32 tiles = 2048 blocks of 256 threads
__global__ __launch_bounds__(256) void kA(const float* __restrict__ pred,
                                          const float* __restrict__ noisy,
                                          const int* __restrict__ mask,
                                          float* __restrict__ acc,
                                          float* __restrict__ ll1) {
    __shared__ float lds[17 * LDS_STRIDE];
    __shared__ float red[4][4];

    const int bid = blockIdx.x;
    const int n = bid >> 5;          // image
    const int tile = bid & 31;       // row tile
    const int t0 = tile * TILE_ROWS;
    const size_t base = (size_t)n * (H * W);
    const int tid = threadIdx.x;

    float n2v = 0.0f, msum = 0.0f;

    // Phase 1: load + clip + n2v, stage clipped pred in LDS
#pragma unroll
    for (int k = 0; k < 8; ++k) {
        int q = tid + 256 * k;
        int r = q >> 7;          // 0..15
        int c4 = q & 127;        // float4 column
        size_t off = base + (size_t)(t0 + r) * W + (size_t)c4 * 4;
        float4 p = *reinterpret_cast<const float4*>(pred + off);
        float4 nz = *reinterpret_cast<const float4*>(noisy + off);
        int4 mk = *reinterpret_cast<const int4*>(mask + off);
        p.x = clip01(p.x); p.y = clip01(p.y); p.z = clip01(p.z); p.w = clip01(p.w);
        float m0 = mk.x ? 1.0f : 0.0f;
        float m1 = mk.y ? 1.0f : 0.0f;
        float m2 = mk.z ? 1.0f : 0.0f;
        float m3 = mk.w ? 1.0f : 0.0f;
        n2v += fabsf(p.x - nz.x) * m0 + fabsf(p.y - nz.y) * m1 +
               fabsf(p.z - nz.z) * m2 + fabsf(p.w - nz.w) * m3;
        msum += m0 + m1 + m2 + m3;
        *reinterpret_cast<float4*>(&lds[r * LDS_STRIDE + c4 * 4]) = p;
    }
    // Halo row (previous image row) for vertical TV at tile top
    if (tile > 0 && tid < 128) {
        size_t off = base + (size_t)(t0 - 1) * W + (size_t)tid * 4;
        float4 p = *reinterpret_cast<const float4*>(pred + off);
        p.x = clip01(p.x); p.y = clip01(p.y); p.z = clip01(p.z); p.w = clip01(p.w);
        *reinterpret_cast<float4*>(&lds[16 * LDS_STRIDE + tid * 4]) = p;
    }
    __syncthreads();

    float tv = 0.0f, wav = 0.0f;

    // Phase 2: TV + DWT from LDS
#pragma unroll
    for (int k = 0; k < 8; ++k) {
        int q = tid + 256 * k;
        int r = q >> 7;
        int c4 = q & 127;
        float4 x = *reinterpret_cast<const float4*>(&lds[r * LDS_STRIDE + c4 * 4]);
        // horizontal diffs
        tv += fabsf(x.y - x.x) + fabsf(x.z - x.y) + fabsf(x.w - x.z);
        if (c4 > 0) tv += fabsf(x.x - lds[r * LDS_STRIDE + c4 * 4 - 1]);
        // vertical diffs
        int g = t0 + r;
        if (g >= 1) {
            int rp = (r >= 1) ? (r - 1) : 16;  // 16 = halo row
            float4 y = *reinterpret_cast<const float4*>(&lds[rp * LDS_STRIDE + c4 * 4]);
            tv += fabsf(x.x - y.x) + fabsf(x.y - y.y) +
                  fabsf(x.z - y.z) + fabsf(x.w - y.w);
        }
        // DWT: threads tid<128 own even rows (r = 2k, c4 = tid)
        if (tid < 128) {
            float4 z = *reinterpret_cast<const float4*>(&lds[(r + 1) * LDS_STRIDE + c4 * 4]);
            // quad 0: cols 4c4, 4c4+1
            float a = x.x, b = x.y, c = z.x, d = z.y;
            float ll0 = (a + b + c + d) * 0.5f;
            float ch = (a + b - c - d) * 0.5f;
            float cv = (a - b + c - d) * 0.5f;
            float cd = (a - b - c + d) * 0.5f;
            wav += fminf(fabsf(ch), THR_L3) + fminf(fabsf(cv), THR_L3) + fminf(fabsf(cd), THR_L3);
            // quad 1: cols 4c4+2, 4c4+3
            a = x.z; b = x.w; c = z.z; d = z.w;
            float ll1v = (a + b + c + d) * 0.5f;
            ch = (a + b - c - d) * 0.5f;
            cv = (a - b + c - d) * 0.5f;
            cd = (a - b - c + d) * 0.5f;
            wav += fminf(fabsf(ch), THR_L3) + fminf(fabsf(cv), THR_L3) + fminf(fabsf(cd), THR_L3);
            int llrow = (t0 >> 1) + k;
            float2 o = make_float2(ll0, ll1v);
            *reinterpret_cast<float2*>(ll1 + (size_t)n * 65536 + llrow * 256 + 2 * c4) = o;
        }
    }

    // Block reduction: 4 quantities
    float v0 = wave_sum(n2v);
    float v1 = wave_sum(msum);
    float v2 = wave_sum(tv);
    float v3 = wave_sum(wav);
    int lane = tid & 63, wid = tid >> 6;
    if (lane == 0) { red[wid][0] = v0; red[wid][1] = v1; red[wid][2] = v2; red[wid][3] = v3; }
    __syncthreads();
    if (tid == 0) {
        atomicAdd(acc + 0, red[0][0] + red[1][0] + red[2][0] + red[3][0]);
        atomicAdd(acc + 1, red[0][1] + red[1][1] + red[2][1] + red[3][1]);
        atomicAdd(acc + 2, red[0][2] + red[1][2] + red[2][2] + red[3][2]);
        atomicAdd(acc + 3, red[0][3] + red[1][3] + red[2][3] + red[3][3]);
    }
}

// Kernel B: level-2 DWT on ll1 (64x256x256) -> ll2 (64x128x128)
__global__ __launch_bounds__(256) void kB(const float* __restrict__ ll1,
                                          float* __restrict__ ll2,
                                          float* __restrict__ acc) {
    __shared__ float red[4];
    int i = blockIdx.x * 256 + threadIdx.x;
    int n = i >> 14;
    int rem = i & 16383;
    int qr = rem >> 7;
    int qc = rem & 127;
    const float* src = ll1 + (size_t)n * 65536;
    float2 top = *reinterpret_cast<const float2*>(src + (2 * qr) * 256 + 2 * qc);
    float2 bot = *reinterpret_cast<const float2*>(src + (2 * qr + 1) * 256 + 2 * qc);
    float a = top.x, b = top.y, c = bot.x, d = bot.y;
    ll2[(size_t)n * 16384 + qr * 128 + qc] = (a + b + c + d) * 0.5f;
    float ch = (a + b - c - d) * 0.5f;
    float cv = (a - b + c - d) * 0.5f;
    float cd = (a - b - c + d) * 0.5f;
    float wav = fminf(fabsf(ch), THR_L2) + fminf(fabsf(cv), THR_L2) + fminf(fabsf(cd), THR_L2);
    wav = wave_sum(wav);
    int lane = threadIdx.x & 63, wid = threadIdx.x >> 6;
    if (lane == 0) red[wid] = wav;
    __syncthreads();
    if (threadIdx.x == 0) atomicAdd(acc + 4, red[0] + red[1] + red[2] + red[3]);
}

// Kernel C: level-3 DWT on ll2 (64x128x128) -> details only (64x64)
__global__ __launch_bounds__(256) void kC(const float* __restrict__ ll2,
                                          float* __restrict__ acc) {
    __shared__ float red[4];
    int i = blockIdx.x * 256 + threadIdx.x;
    int n = i >> 12;
    int rem = i & 4095;
    int qr = rem >> 6;
    int qc = rem & 63;
    const float* src = ll2 + (size_t)n * 16384;
    float2 top = *reinterpret_cast<const float2*>(src + (2 * qr) * 128 + 2 * qc);
    float2 bot = *reinterpret_cast<const float2*>(src + (2 * qr + 1) * 128 + 2 * qc);
    float a = top.x, b = top.y, c = bot.x, d = bot.y;
    float ch = (a + b - c - d) * 0.5f;
    float cv = (a - b + c - d) * 0.5f;
    float cd = (a - b - c + d) * 0.5f;
    float wav = fminf(fabsf(ch), THR_L1) + fminf(fabsf(cv), THR_L1) + fminf(fabsf(cd), THR_L1);
    wav = wave_sum(wav);
    int lane = threadIdx.x & 63, wid = threadIdx.x >> 6;
    if (lane == 0) red[wid] = wav;
    __syncthreads();
    if (threadIdx.x == 0) atomicAdd(acc + 5, red[0] + red[1] + red[2] + red[3]);
}

// Kernel D: compose final scalar
__global__ void kD(const float* __restrict__ acc, float* __restrict__ out) {
    float n2v = acc[0] / fmaxf(acc[1], 1.0f);
    float tv = acc[2] / 16744448.0f;                       // 64*511*512 (both terms)
    float wav = acc[3] * (1.0f / 37748736.0f)              // (1/3) / (3*64*256*256)
              + acc[4] * (1.0f / 6291456.0f)               // (1/2) / (3*64*128*128)
              + acc[5] * (1.0f / 786432.0f);               // 1     / (3*64*64*64)
    out[0] = 1.0f * n2v + 0.2f * wav + 0.01f * tv;
}

extern "C" void kernel_launch(void* const* d_in, const int* in_sizes, int n_in,
                              void* d_out, int out_size, void* d_ws, size_t ws_size,
                              hipStream_t stream) {
    (void)in_sizes; (void)n_in; (void)out_size; (void)ws_size;
    const float* pred  = (const float*)d_in[0];
    const float* noisy = (const float*)d_in[1];
    const int*   mask  = (const int*)d_in[2];

    float* acc = (float*)d_ws;                 // 6 accumulators (64-float slab)
    float* ll1 = (float*)d_ws + 64;            // 64*256*256 floats = 16 MB
    float* ll2 = ll1 + (size_t)NIMG * 256 * 256; // 64*128*128 floats = 4 MB

    hipMemsetAsync(d_ws, 0, 64 * sizeof(float), stream);
    kA<<<NIMG * 32, 256, 0, stream>>>(pred, noisy, mask, acc, ll1);
    kB<<<(NIMG * 128 * 128) / 256, 256, 0, stream>>>(ll1, ll2, acc);
    kC<<<(NIMG * 64 * 64) / 256, 256, 0, stream>>>(ll2, acc);
    kD<<<1, 1, 0, stream>>>(acc, (float*)d_out);
}